// Round 21
// baseline (147.820 us; speedup 1.0000x reference)
//
#include <hip/hip_runtime.h>

typedef __bf16 bf16x8 __attribute__((ext_vector_type(8)));
typedef float f32x4 __attribute__((ext_vector_type(4)));
typedef float f32x16 __attribute__((ext_vector_type(16)));

constexpr int SEQ = 2048;
constexpr int DMODEL = 1024;

#define GLL(gp, lp)                                                              \
  __builtin_amdgcn_global_load_lds((const __attribute__((address_space(1))) void*)(gp), \
                                   (__attribute__((address_space(3))) void*)(lp), 16, 0, 0)

// ---------------- merged prep: sincos table + weight transposes + x convert ----------------
__global__ __launch_bounds__(256) void prep_kernel(const float* __restrict__ x,
                                                   const float* __restrict__ Wqkv,
                                                   const float* __restrict__ Wo,
                                                   __bf16* __restrict__ xbf,
                                                   __bf16* __restrict__ WqkvT,
                                                   __bf16* __restrict__ WoT,
                                                   float2* __restrict__ sct) {
  __shared__ __bf16 tile[64][72];
  int blk = blockIdx.x, t = threadIdx.x;

  if (blk < 256) {  // sct[t][j] = (cos, sin)(t * 10000^(-j/32))
    int i = blk * 256 + t;
    int tt = i >> 5, j = i & 31;
    float theta = exp2f(-(float)j * 0.41524101186092953f);
    float s, c;
    __sincosf((float)tt * theta, &s, &c);
    sct[i] = make_float2(c, s);
    return;
  }
  if (blk >= 1280) {  // cvt x -> bf16
    size_t i = (size_t)(blk - 1280) * 256 + t;
    const float* sp = x + i * 8;
    float4 f0 = *reinterpret_cast<const float4*>(sp);
    float4 f1 = *reinterpret_cast<const float4*>(sp + 4);
    alignas(16) __bf16 tmp[8];
    tmp[0] = (__bf16)f0.x; tmp[1] = (__bf16)f0.y; tmp[2] = (__bf16)f0.z; tmp[3] = (__bf16)f0.w;
    tmp[4] = (__bf16)f1.x; tmp[5] = (__bf16)f1.y; tmp[6] = (__bf16)f1.z; tmp[7] = (__bf16)f1.w;
    *reinterpret_cast<uint4*>(xbf + i * 8) = *reinterpret_cast<const uint4*>(tmp);
    return;
  }
  const float* src;
  __bf16* dst;
  int C, R, c0, r0;
  if (blk < 512) {
    int idx = blk - 256;
    src = Wo; dst = WoT; R = 1024; C = 1024;
    c0 = (idx & 15) * 64; r0 = (idx >> 4) * 64;
  } else {
    int idx = blk - 512;
    src = Wqkv; dst = WqkvT; R = 1024; C = 3072;
    c0 = (idx % 48) * 64; r0 = (idx / 48) * 64;
  }
#pragma unroll
  for (int p = 0; p < 2; ++p) {
    int flat = p * 256 + t;
    int i = flat >> 3;
    int j8 = (flat & 7) * 8;
    const float* sp = &src[(size_t)(r0 + i) * C + c0 + j8];
    float4 f0 = *reinterpret_cast<const float4*>(sp);
    float4 f1 = *reinterpret_cast<const float4*>(sp + 4);
    tile[i][j8 + 0] = (__bf16)f0.x; tile[i][j8 + 1] = (__bf16)f0.y;
    tile[i][j8 + 2] = (__bf16)f0.z; tile[i][j8 + 3] = (__bf16)f0.w;
    tile[i][j8 + 4] = (__bf16)f1.x; tile[i][j8 + 5] = (__bf16)f1.y;
    tile[i][j8 + 6] = (__bf16)f1.z; tile[i][j8 + 7] = (__bf16)f1.w;
  }
  __syncthreads();
#pragma unroll
  for (int p = 0; p < 2; ++p) {
    int flat = p * 256 + t;
    int i = flat >> 3;
    int j8 = (flat & 7) * 8;
    alignas(16) __bf16 tmp[8];
#pragma unroll
    for (int jj = 0; jj < 8; ++jj) tmp[jj] = tile[j8 + jj][i];
    *reinterpret_cast<uint4*>(&dst[(size_t)(c0 + i) * R + r0 + j8]) =
        *reinterpret_cast<const uint4*>(tmp);
  }
}

// ---------------- GEMM (m97 structure, 512 threads / 8 waves, T2-swizzled LDS) ----------------
// LDS physical layout: elem' = elem ^ (8*(row&7)) (pre-swizzled GLL source; XOR on read).
template <typename CT, int BN, int MODE>
__global__ __launch_bounds__(512, 6) void gemm_bt_lds(const __bf16* __restrict__ A,
                                                      const __bf16* __restrict__ BT,
                                                      CT* __restrict__ C,
                                                      int M, int N, int K, int lda, int ldc,
                                                      const float2* __restrict__ sct,
                                                      __bf16* __restrict__ vt) {
  constexpr int NF = BN / 32;
  __shared__ __align__(16) __bf16 AB_lds[128 + BN][64];
  __bf16 (*A_lds)[64] = &AB_lds[0];
  __bf16 (*B_lds)[64] = &AB_lds[128];

  int tid = threadIdx.x;
  int lane = tid & 63, w = tid >> 6;
  int g = lane >> 4, l15 = lane & 15;
  int wr = w & 3;
  int wc = w >> 2;
  int m0 = blockIdx.x * 128;
  int n0 = blockIdx.y * BN;
  int r8 = lane >> 3;
  int cxe = 8 * ((lane & 7) ^ r8);  // pre-swizzled source column

  const __bf16* ag = A + (size_t)(m0 + w * 16 + r8) * lda + cxe;
  const __bf16* bg = BT + (size_t)(n0 + w * (BN / 8) + r8) * K + cxe;

  int sxa = 8 * (l15 & 7);  // read-side XOR

  f32x4 acc[2][NF] = {};

  for (int k0 = 0; k0 < K; k0 += 64) {
    __syncthreads();
    GLL(ag + k0, &A_lds[w * 16][0]);
    GLL(ag + (size_t)8 * lda + k0, &A_lds[w * 16 + 8][0]);
    if constexpr (BN == 128) {
      GLL(bg + k0, &B_lds[w * 16][0]);
      GLL(bg + (size_t)8 * K + k0, &B_lds[w * 16 + 8][0]);
    } else {
      GLL(bg + k0, &B_lds[w * 8][0]);
    }
    __syncthreads();
#pragma unroll
    for (int kk = 0; kk < 2; ++kk) {
      int col = (kk * 32 + g * 8) ^ sxa;
      bf16x8 a[2], bb[NF];
#pragma unroll
      for (int m = 0; m < 2; ++m)
        a[m] = *reinterpret_cast<const bf16x8*>(&A_lds[wr * 32 + m * 16 + l15][col]);
#pragma unroll
      for (int n = 0; n < NF; ++n)
        bb[n] = *reinterpret_cast<const bf16x8*>(&B_lds[wc * (BN / 2) + n * 16 + l15][col]);
#pragma unroll
      for (int m = 0; m < 2; ++m)
#pragma unroll
        for (int n = 0; n < NF; ++n)
          acc[m][n] = __builtin_amdgcn_mfma_f32_16x16x32_bf16(a[m], bb[n], acc[m][n], 0, 0, 0);
    }
  }

  if constexpr (MODE == 3) {
    if (n0 >= 2048) {
      __bf16 (*T_lds)[72] = reinterpret_cast<__bf16(*)[72]>(&AB_lds[0][0]);
      int b = m0 >> 11;
      int s_base = m0 & (SEQ - 1);
#pragma unroll
      for (int half = 0; half < 2; ++half) {
        __syncthreads();
        if (wc == half) {
#pragma unroll
          for (int m = 0; m < 2; ++m)
#pragma unroll
            for (int n = 0; n < NF; ++n)
#pragma unroll
              for (int r = 0; r < 4; ++r)
                T_lds[wr * 32 + m * 16 + 4 * g + r][n * 16 + l15] = (__bf16)acc[m][n][r];
        }
        __syncthreads();
        int head = ((n0 - 2048) >> 6) + half;
        int bh = b * 16 + head;
        int d = tid >> 3;
        int s8 = (tid & 7) * 16;
        __bf16* dst = vt + (size_t)bh * 64 * SEQ + (size_t)d * SEQ + s_base + s8;
#pragma unroll
        for (int j = 0; j < 2; ++j) {
          alignas(16) __bf16 tmp[8];
#pragma unroll
          for (int e = 0; e < 8; ++e) tmp[e] = T_lds[s8 + j * 8 + e][d];
          *reinterpret_cast<uint4*>(dst + j * 8) = *reinterpret_cast<const uint4*>(tmp);
        }
      }
      return;
    }
    bool isq = (n0 < 1024);
    float sc = isq ? 0.18033688011112042f : 1.0f;  // 0.125 * log2(e) for q (exp2 softmax)
#pragma unroll
    for (int m = 0; m < 2; ++m)
#pragma unroll
      for (int r = 0; r < 4; ++r) {
        int row = m0 + wr * 32 + m * 16 + 4 * g + r;
        int t = row & (SEQ - 1);
#pragma unroll
        for (int n = 0; n < 2; ++n) {
          int j = n * 16 + l15;
          float2 cs = sct[(t << 5) + j];
          float x1 = acc[m][n][r], x2 = acc[m][n + 2][r];
          acc[m][n][r]     = (x1 * cs.x - x2 * cs.y) * sc;
          acc[m][n + 2][r] = (x1 * cs.y + x2 * cs.x) * sc;
        }
      }
  }

#pragma unroll
  for (int m = 0; m < 2; ++m)
#pragma unroll
    for (int n = 0; n < NF; ++n)
#pragma unroll
      for (int r = 0; r < 4; ++r) {
        int row = m0 + wr * 32 + m * 16 + 4 * g + r;
        int col = n0 + wc * (BN / 2) + n * 16 + l15;
        C[(size_t)row * ldc + col] = (CT)acc[m][n][r];
      }
}

__device__ inline uint32_t pkbf(float a, float b) {
  union { __bf16 h[2]; uint32_t u; } z;
  z.h[0] = (__bf16)a; z.h[1] = (__bf16)b;
  return z.u;
}

// partial O-slot base for global slot gi in [0,2048)
__device__ inline __bf16* slot_base(int gi, __bf16* qkv, __bf16* xbf, int q_local) {
  if (gi < 1024)
    return qkv + (size_t)(gi * 4 + (q_local >> 4)) * 3072 + 2048 + (q_local & 15) * 64;
  return xbf + (size_t)(gi - 1024) * 4096 + (size_t)q_local * 64;
}

// ---------------- causal flash attention: BARRIER-FREE, zero-LDS, split-K (2048 blocks) ----------------
// K and V^T both read global->reg (L2-resident); no LDS, no __syncthreads, no explicit waitcnt.
// Waves drift freely; waits are compiler data-dep counted. STATIC-max softmax (m=8, exp2).
__global__ __launch_bounds__(128, 4) void attn_kernel(__bf16* __restrict__ qkv,
                                                      const __bf16* __restrict__ vt,
                                                      __bf16* __restrict__ xbf,
                                                      float* __restrict__ pml) {
  int tid = threadIdx.x;
  int w = tid >> 6, lane = tid & 63;
  int l31 = lane & 31, hi = lane >> 5;
  int bid = blockIdx.x;
  int it = bid >> 5, bh = bid & 31;
  int b = bh >> 4, h = bh & 15;

  int qc = 31 - (it >> 1);
  int half = it & 1;
  int NTf = qc + 1;
  int hs = (NTf + 1) >> 1;
  int kv0 = half ? hs : 0;
  int kv1 = half ? NTf : hs;
  int NT = kv1 - kv0;

  __bf16* qbase = qkv + (size_t)b * SEQ * 3072 + h * 64;
  const __bf16* kbase = qbase + 1024;
  const __bf16* vtb = vt + (size_t)bh * 64 * SEQ;

  int q_g = qc * 64 + w * 32 + l31;

  bf16x8 qf[4];
#pragma unroll
  for (int ds = 0; ds < 4; ++ds)
    qf[ds] = *reinterpret_cast<const bf16x8*>(qbase + (size_t)q_g * 3072 + ds * 16 + 8 * hi);

  f32x16 oacc[2] = {};
  float l_run = 0.f;
  const float MFIX = 8.0f;

  // per-lane K row base: row = kt_g*64 + kt*32 + l31, col = ds*16 + 8*hi
  const __bf16* krow = kbase + (size_t)l31 * 3072 + 8 * hi;

  for (int jb = 0; jb < NT; ++jb) {
    int kt_g = kv0 + jb;

    // ---- K fragments (global->reg) ----
    bf16x8 kf[2][4];
#pragma unroll
    for (int kt = 0; kt < 2; ++kt)
#pragma unroll
      for (int ds = 0; ds < 4; ++ds)
        kf[kt][ds] = *reinterpret_cast<const bf16x8*>(
            krow + (size_t)(kt_g * 64 + kt * 32) * 3072 + ds * 16);

    // ---- S^T = K · Q^T ----
    f32x16 sacc[2] = {};
    __builtin_amdgcn_s_setprio(1);
#pragma unroll
    for (int kt = 0; kt < 2; ++kt)
#pragma unroll
      for (int ds = 0; ds < 4; ++ds)
        sacc[kt] = __builtin_amdgcn_mfma_f32_32x32x16_bf16(kf[kt][ds], qf[ds], sacc[kt], 0, 0, 0);
    __builtin_amdgcn_s_setprio(0);

    // ---- V^T loads issued now: in flight across softmax ----
    uint4 vr[8];
#pragma unroll
    for (int dt = 0; dt < 2; ++dt)
#pragma unroll
      for (int ks = 0; ks < 4; ++ks)
        vr[dt * 4 + ks] = *reinterpret_cast<const uint4*>(
            vtb + (size_t)(dt * 32 + l31) * SEQ + kt_g * 64 + ks * 16 + 8 * hi);

    // ---- causal mask on the diagonal tile ----
    if (kt_g == qc) {
#pragma unroll
      for (int kt = 0; kt < 2; ++kt)
#pragma unroll
        for (int r = 0; r < 16; ++r) {
          int k_g = kt_g * 64 + kt * 32 + (r & 3) + 8 * (r >> 2) + 4 * hi;
          if (k_g > q_g) sacc[kt][r] = -1e30f;
        }
    }

    // ---- p = exp2(s - MFIX); 4 parallel sum chains ----
    float s0 = 0.f, s1 = 0.f, s2 = 0.f, s3 = 0.f;
#pragma unroll
    for (int kt = 0; kt < 2; ++kt) {
#pragma unroll
      for (int r = 0; r < 16; r += 4) {
        float p0 = exp2f(sacc[kt][r + 0] - MFIX);
        float p1 = exp2f(sacc[kt][r + 1] - MFIX);
        float p2 = exp2f(sacc[kt][r + 2] - MFIX);
        float p3 = exp2f(sacc[kt][r + 3] - MFIX);
        sacc[kt][r + 0] = p0; sacc[kt][r + 1] = p1;
        sacc[kt][r + 2] = p2; sacc[kt][r + 3] = p3;
        s0 += p0; s1 += p1; s2 += p2; s3 += p3;
      }
    }
    float sum = (s0 + s1) + (s2 + s3);
    sum += __shfl_xor(sum, 32);
    l_run += sum;

    // ---- build P fragments ----
    uint4 pa[4];
#pragma unroll
    for (int ks = 0; ks < 4; ++ks) {
      int v0 = 2 * ks, v1 = v0 + 1;
      int t0 = v0 >> 2, rb0 = 4 * (v0 & 3);
      int t1 = v1 >> 2, rb1 = 4 * (v1 & 3);
      uint32_t a01, a23, b01, b23;
      if (t0 == 0) { a01 = pkbf(sacc[0][rb0 + 0], sacc[0][rb0 + 1]);
                     a23 = pkbf(sacc[0][rb0 + 2], sacc[0][rb0 + 3]); }
      else         { a01 = pkbf(sacc[1][rb0 + 0], sacc[1][rb0 + 1]);
                     a23 = pkbf(sacc[1][rb0 + 2], sacc[1][rb0 + 3]); }
      if (t1 == 0) { b01 = pkbf(sacc[0][rb1 + 0], sacc[0][rb1 + 1]);
                     b23 = pkbf(sacc[0][rb1 + 2], sacc[0][rb1 + 3]); }
      else         { b01 = pkbf(sacc[1][rb1 + 0], sacc[1][rb1 + 1]);
                     b23 = pkbf(sacc[1][rb1 + 2], sacc[1][rb1 + 3]); }
      uint32_t t01 = hi ? a01 : b01;
      uint32_t t23 = hi ? a23 : b23;
      uint32_t r01 = __shfl_xor(t01, 32);
      uint32_t r23 = __shfl_xor(t23, 32);
      uint32_t k01 = hi ? b01 : a01;
      uint32_t k23 = hi ? b23 : a23;
      pa[ks].x = hi ? r01 : k01;
      pa[ks].y = hi ? r23 : k23;
      pa[ks].z = hi ? k01 : r01;
      pa[ks].w = hi ? k23 : r23;
    }

    // ---- O^T += V^T · P^T (V from regs; compiler waits vr via data deps) ----
    __builtin_amdgcn_s_setprio(1);
#pragma unroll
    for (int dt = 0; dt < 2; ++dt) {
#pragma unroll
      for (int ks = 0; ks < 4; ++ks) {
        oacc[dt] = __builtin_amdgcn_mfma_f32_32x32x16_bf16(
            *reinterpret_cast<const bf16x8*>(&vr[dt * 4 + ks]),
            *reinterpret_cast<const bf16x8*>(&pa[ks]), oacc[dt], 0, 0, 0);
      }
    }
    __builtin_amdgcn_s_setprio(0);
  }

  // partial: unnormalized O^T (bf16) + l  (ALL items)
  int gi = ((31 - qc) * 2 + half) * 32 + bh;
  int q_local = w * 32 + l31;
  __bf16* pobase = slot_base(gi, qkv, xbf, q_local);
#pragma unroll
  for (int dt = 0; dt < 2; ++dt)
#pragma unroll
    for (int u = 0; u < 4; ++u) {
      int d0 = dt * 32 + 8 * u + 4 * hi;
      alignas(8) __bf16 tmp[4];
#pragma unroll
      for (int m = 0; m < 4; ++m) tmp[m] = (__bf16)oacc[dt][4 * u + m];
      *reinterpret_cast<uint2*>(pobase + d0) = *reinterpret_cast<const uint2*>(tmp);
    }
  if (hi == 0) pml[gi * 128 + q_local] = l_run;
}

// ---------------- combine halves (static max => pure l-weighting) ----------------
__global__ __launch_bounds__(128) void combine_kernel(__bf16* __restrict__ qkv,
                                                      __bf16* __restrict__ xbf,
                                                      const float* __restrict__ pml) {
  int bid = blockIdx.x;  // 1024 = 32 qc * 32 bh
  int qc = 31 - (bid >> 5), bh = bid & 31;
  int b = bh >> 4, h = bh & 15;
  int t = threadIdx.x;
  int q = t >> 1, dh = (t & 1) * 32;

  int g0 = ((31 - qc) * 2 + 0) * 32 + bh;
  int g1 = g0 + 32;
  float l0 = pml[g0 * 128 + q];
  float l1 = pml[g1 * 128 + q];
  float inv = 1.0f / (l0 + l1);

  const __bf16* p0 = slot_base(g0, qkv, xbf, q) + dh;
  const __bf16* p1 = slot_base(g1, qkv, xbf, q) + dh;
  __bf16* yq = qkv + (size_t)(b * SEQ + qc * 64 + q) * 3072 + h * 64 + dh;

#pragma unroll
  for (int c = 0; c < 4; ++c) {
    uint4 ua = *reinterpret_cast<const uint4*>(p0 + c * 8);
    uint4 ub = *reinterpret_cast<const uint4*>(p1 + c * 8);
    const __bf16* va = reinterpret_cast<const __bf16*>(&ua);
    const __bf16* vb = reinterpret_cast<const __bf16*>(&ub);
    alignas(16) __bf16 outv[8];
#pragma unroll
    for (int j = 0; j < 8; ++j)
      outv[j] = (__bf16)((((float)va[j]) + ((float)vb[j])) * inv);
    *reinterpret_cast<uint4*>(yq + c * 8) = *reinterpret_cast<const uint4*>(outv);
  }
}

extern "C" void kernel_launch(void* const* d_in, const int* in_sizes, int n_in,
                              void* d_out, int out_size, void* d_ws, size_t ws_size,
                              hipStream_t stream) {
  const float* x = (const float*)d_in[0];
  const float* Wqkv = (const float*)d_in[1];
  const float* Wo = (const float*)d_in[2];
  float* out = (float*)d_out;

  // ws layout (bf16 element offsets)
  __bf16* ws = (__bf16*)d_ws;
  __bf16* WqkvT = ws;                           // [3072][1024]  6 MB
  __bf16* WoT = WqkvT + (size_t)3072 * 1024;    // [1024][1024]  2 MB
  __bf16* qkv = WoT + (size_t)1024 * 1024;      // [4096][3072] 24 MB (v-slot = partial slots)
  __bf16* xbf = qkv + (size_t)4096 * 3072;      // [4096][1024]  8 MB (partial slots 1024..2047)
  __bf16* vtb = xbf + (size_t)4096 * 1024;      // [32][64][2048] 8 MB
  float* pml = (float*)(vtb + (size_t)32 * 64 * SEQ);  // 2048*128 f32 = 1 MB
  float2* sct = (float2*)(pml + 2048 * 128);           // 2048*32 float2 = 512 KB

  // 1) prep
  prep_kernel<<<3328, 256, 0, stream>>>(x, Wqkv, Wo, xbf, WqkvT, WoT, sct);

  // 2) merged qkv gemm (512-thread, T2-swizzled LDS): qk RoPE'd -> qkv; v -> vtb
  gemm_bt_lds<__bf16, 128, 3><<<dim3(32, 24), 512, 0, stream>>>(
      xbf, WqkvT, qkv, 4096, 3072, 1024, 1024, 3072, sct, vtb);

  // 3) attention: barrier-free zero-LDS split-K, 2048 blocks
  attn_kernel<<<2048, 128, 0, stream>>>(qkv, vtb, xbf, pml);

  // 4) combine halves
  combine_kernel<<<1024, 128, 0, stream>>>(qkv, xbf, pml);

  // 5) out = y @ Wo (512-thread, T2-swizzled LDS)
  gemm_bt_lds<float, 64, 0><<<dim3(32, 16), 512, 0, stream>>>(
      qkv, WoT, out, 4096, 1024, 1024, 3072, 1024, sct, nullptr);
}

// Round 22
// 118.809 us; speedup vs baseline: 1.2442x; 1.2442x over previous
//
#include <hip/hip_runtime.h>

typedef __bf16 bf16x8 __attribute__((ext_vector_type(8)));
typedef float f32x4 __attribute__((ext_vector_type(4)));
typedef float f32x16 __attribute__((ext_vector_type(16)));

constexpr int SEQ = 2048;
constexpr int DMODEL = 1024;

#define GLL(gp, lp)                                                              \
  __builtin_amdgcn_global_load_lds((const __attribute__((address_space(1))) void*)(gp), \
                                   (__attribute__((address_space(3))) void*)(lp), 16, 0, 0)

// ---------------- merged prep: sincos table + weight transposes + x convert ----------------
__global__ __launch_bounds__(256) void prep_kernel(const float* __restrict__ x,
                                                   const float* __restrict__ Wqkv,
                                                   const float* __restrict__ Wo,
                                                   __bf16* __restrict__ xbf,
                                                   __bf16* __restrict__ WqkvT,
                                                   __bf16* __restrict__ WoT,
                                                   float2* __restrict__ sct) {
  __shared__ __bf16 tile[64][72];
  int blk = blockIdx.x, t = threadIdx.x;

  if (blk < 256) {  // sct[t][j] = (cos, sin)(t * 10000^(-j/32))
    int i = blk * 256 + t;
    int tt = i >> 5, j = i & 31;
    float theta = exp2f(-(float)j * 0.41524101186092953f);
    float s, c;
    __sincosf((float)tt * theta, &s, &c);
    sct[i] = make_float2(c, s);
    return;
  }
  if (blk >= 1280) {  // cvt x -> bf16
    size_t i = (size_t)(blk - 1280) * 256 + t;
    const float* sp = x + i * 8;
    float4 f0 = *reinterpret_cast<const float4*>(sp);
    float4 f1 = *reinterpret_cast<const float4*>(sp + 4);
    alignas(16) __bf16 tmp[8];
    tmp[0] = (__bf16)f0.x; tmp[1] = (__bf16)f0.y; tmp[2] = (__bf16)f0.z; tmp[3] = (__bf16)f0.w;
    tmp[4] = (__bf16)f1.x; tmp[5] = (__bf16)f1.y; tmp[6] = (__bf16)f1.z; tmp[7] = (__bf16)f1.w;
    *reinterpret_cast<uint4*>(xbf + i * 8) = *reinterpret_cast<const uint4*>(tmp);
    return;
  }
  const float* src;
  __bf16* dst;
  int C, R, c0, r0;
  if (blk < 512) {
    int idx = blk - 256;
    src = Wo; dst = WoT; R = 1024; C = 1024;
    c0 = (idx & 15) * 64; r0 = (idx >> 4) * 64;
  } else {
    int idx = blk - 512;
    src = Wqkv; dst = WqkvT; R = 1024; C = 3072;
    c0 = (idx % 48) * 64; r0 = (idx / 48) * 64;
  }
#pragma unroll
  for (int p = 0; p < 2; ++p) {
    int flat = p * 256 + t;
    int i = flat >> 3;
    int j8 = (flat & 7) * 8;
    const float* sp = &src[(size_t)(r0 + i) * C + c0 + j8];
    float4 f0 = *reinterpret_cast<const float4*>(sp);
    float4 f1 = *reinterpret_cast<const float4*>(sp + 4);
    tile[i][j8 + 0] = (__bf16)f0.x; tile[i][j8 + 1] = (__bf16)f0.y;
    tile[i][j8 + 2] = (__bf16)f0.z; tile[i][j8 + 3] = (__bf16)f0.w;
    tile[i][j8 + 4] = (__bf16)f1.x; tile[i][j8 + 5] = (__bf16)f1.y;
    tile[i][j8 + 6] = (__bf16)f1.z; tile[i][j8 + 7] = (__bf16)f1.w;
  }
  __syncthreads();
#pragma unroll
  for (int p = 0; p < 2; ++p) {
    int flat = p * 256 + t;
    int i = flat >> 3;
    int j8 = (flat & 7) * 8;
    alignas(16) __bf16 tmp[8];
#pragma unroll
    for (int jj = 0; jj < 8; ++jj) tmp[jj] = tile[j8 + jj][i];
    *reinterpret_cast<uint4*>(&dst[(size_t)(c0 + i) * R + r0 + j8]) =
        *reinterpret_cast<const uint4*>(tmp);
  }
}

// ---------------- GEMM (m97 structure, 512 threads / 8 waves, T2-swizzled LDS) ----------------
// LDS physical layout: elem' = elem ^ (8*(row&7)) (pre-swizzled GLL source; XOR on read).
// Wave w: wr = w&3 (32-row block), wc = w>>2 (BN/2-col block).
// MODE 0: plain C write. MODE 3: merged qkv gemm (RoPE epilogue on q/k; v -> vt via LDS).
template <typename CT, int BN, int MODE>
__global__ __launch_bounds__(512, 6) void gemm_bt_lds(const __bf16* __restrict__ A,
                                                      const __bf16* __restrict__ BT,
                                                      CT* __restrict__ C,
                                                      int M, int N, int K, int lda, int ldc,
                                                      const float2* __restrict__ sct,
                                                      __bf16* __restrict__ vt) {
  constexpr int NF = BN / 32;  // n-frags per wave: 4 (BN=128) or 2 (BN=64)
  __shared__ __align__(16) __bf16 AB_lds[128 + BN][64];
  __bf16 (*A_lds)[64] = &AB_lds[0];
  __bf16 (*B_lds)[64] = &AB_lds[128];

  int tid = threadIdx.x;
  int lane = tid & 63, w = tid >> 6;
  int g = lane >> 4, l15 = lane & 15;
  int wr = w & 3;    // row block (32 rows)
  int wc = w >> 2;   // col block (BN/2 cols)
  int m0 = blockIdx.x * 128;
  int n0 = blockIdx.y * BN;
  int r8 = lane >> 3;
  int cxe = 8 * ((lane & 7) ^ r8);  // pre-swizzled source column (elem' = elem ^ 8*(row&7))

  const __bf16* ag = A + (size_t)(m0 + w * 16 + r8) * lda + cxe;
  const __bf16* bg = BT + (size_t)(n0 + w * (BN / 8) + r8) * K + cxe;

  int sxa = 8 * (l15 & 7);  // read-side XOR for rows ...*16 + l15 (row&7 == l15&7)

  f32x4 acc[2][NF] = {};

  for (int k0 = 0; k0 < K; k0 += 64) {
    __syncthreads();
    GLL(ag + k0, &A_lds[w * 16][0]);
    GLL(ag + (size_t)8 * lda + k0, &A_lds[w * 16 + 8][0]);
    if constexpr (BN == 128) {
      GLL(bg + k0, &B_lds[w * 16][0]);
      GLL(bg + (size_t)8 * K + k0, &B_lds[w * 16 + 8][0]);
    } else {
      GLL(bg + k0, &B_lds[w * 8][0]);
    }
    __syncthreads();
#pragma unroll
    for (int kk = 0; kk < 2; ++kk) {
      int col = (kk * 32 + g * 8) ^ sxa;
      bf16x8 a[2], bb[NF];
#pragma unroll
      for (int m = 0; m < 2; ++m)
        a[m] = *reinterpret_cast<const bf16x8*>(&A_lds[wr * 32 + m * 16 + l15][col]);
#pragma unroll
      for (int n = 0; n < NF; ++n)
        bb[n] = *reinterpret_cast<const bf16x8*>(&B_lds[wc * (BN / 2) + n * 16 + l15][col]);
#pragma unroll
      for (int m = 0; m < 2; ++m)
#pragma unroll
        for (int n = 0; n < NF; ++n)
          acc[m][n] = __builtin_amdgcn_mfma_f32_16x16x32_bf16(a[m], bb[n], acc[m][n], 0, 0, 0);
    }
  }

  if constexpr (MODE == 3) {
    if (n0 >= 2048) {
      // v columns -> vt[bh][d][s] via LDS re-transpose; T_lds overlays AB_lds (dead now)
      __bf16 (*T_lds)[72] = reinterpret_cast<__bf16(*)[72]>(&AB_lds[0][0]);
      int b = m0 >> 11;
      int s_base = m0 & (SEQ - 1);
#pragma unroll
      for (int half = 0; half < 2; ++half) {
        __syncthreads();
        if (wc == half) {
#pragma unroll
          for (int m = 0; m < 2; ++m)
#pragma unroll
            for (int n = 0; n < NF; ++n)
#pragma unroll
              for (int r = 0; r < 4; ++r)
                T_lds[wr * 32 + m * 16 + 4 * g + r][n * 16 + l15] = (__bf16)acc[m][n][r];
        }
        __syncthreads();
        int head = ((n0 - 2048) >> 6) + half;
        int bh = b * 16 + head;
        int d = tid >> 3;           // 0..63
        int s8 = (tid & 7) * 16;    // 0..112
        __bf16* dst = vt + (size_t)bh * 64 * SEQ + (size_t)d * SEQ + s_base + s8;
#pragma unroll
        for (int j = 0; j < 2; ++j) {
          alignas(16) __bf16 tmp[8];
#pragma unroll
          for (int e = 0; e < 8; ++e) tmp[e] = T_lds[s8 + j * 8 + e][d];
          *reinterpret_cast<uint4*>(dst + j * 8) = *reinterpret_cast<const uint4*>(tmp);
        }
      }
      return;
    }
    // q/k columns: RoPE epilogue. wave's 64-col span = one head; pairs (n, n+2) <-> (d, d+32)
    bool isq = (n0 < 1024);
    float sc = isq ? 0.18033688011112042f : 1.0f;  // 0.125 * log2(e) for q (exp2 softmax)
#pragma unroll
    for (int m = 0; m < 2; ++m)
#pragma unroll
      for (int r = 0; r < 4; ++r) {
        int row = m0 + wr * 32 + m * 16 + 4 * g + r;
        int t = row & (SEQ - 1);
#pragma unroll
        for (int n = 0; n < 2; ++n) {
          int j = n * 16 + l15;  // d in 0..31
          float2 cs = sct[(t << 5) + j];
          float x1 = acc[m][n][r], x2 = acc[m][n + 2][r];
          acc[m][n][r]     = (x1 * cs.x - x2 * cs.y) * sc;
          acc[m][n + 2][r] = (x1 * cs.y + x2 * cs.x) * sc;
        }
      }
  }

#pragma unroll
  for (int m = 0; m < 2; ++m)
#pragma unroll
    for (int n = 0; n < NF; ++n)
#pragma unroll
      for (int r = 0; r < 4; ++r) {
        int row = m0 + wr * 32 + m * 16 + 4 * g + r;
        int col = n0 + wc * (BN / 2) + n * 16 + l15;
        C[(size_t)row * ldc + col] = (CT)acc[m][n][r];
      }
}

__device__ inline uint32_t pkbf(float a, float b) {
  union { __bf16 h[2]; uint32_t u; } z;
  z.h[0] = (__bf16)a; z.h[1] = (__bf16)b;
  return z.u;
}

// partial O-slot base for global slot gi in [0,2048): first 1024 in dead v-slot of qkv,
// next 1024 in dead xbf. Each slot: 64q x 64d bf16 (8 KB).
__device__ inline __bf16* slot_base(int gi, __bf16* qkv, __bf16* xbf, int q_local) {
  if (gi < 1024)
    return qkv + (size_t)(gi * 4 + (q_local >> 4)) * 3072 + 2048 + (q_local & 15) * 64;
  return xbf + (size_t)(gi - 1024) * 4096 + (size_t)q_local * 64;
}

// ---------------- causal flash attention: split-K over ALL qc (2048 blocks) ----------------
// bid -> it = bid>>5 in [0,64), bh = bid&31. qc = 31-(it>>1), half = it&1 (heavy first).
// 2 waves x 32 q-rows. K in LDS (dbuf, swizzled, GLL); V^T read global->reg.
// STATIC-max softmax (m=8, exp2 domain). ALL items write unnormalized O^T partials + l.
__global__ __launch_bounds__(128, 3) void attn_kernel(__bf16* __restrict__ qkv,
                                                      const __bf16* __restrict__ vt,
                                                      __bf16* __restrict__ xbf,
                                                      float* __restrict__ pml) {
  __shared__ __align__(16) __bf16 K_lds[2][64][64];

  int tid = threadIdx.x;
  int w = tid >> 6, lane = tid & 63;
  int l31 = lane & 31, hi = lane >> 5;
  int bid = blockIdx.x;
  int it = bid >> 5, bh = bid & 31;
  int b = bh >> 4, h = bh & 15;

  int qc = 31 - (it >> 1);
  int half = it & 1;
  int NTf = qc + 1;
  int hs = (NTf + 1) >> 1;
  int kv0 = half ? hs : 0;
  int kv1 = half ? NTf : hs;
  int NT = kv1 - kv0;

  __bf16* qbase = qkv + (size_t)b * SEQ * 3072 + h * 64;
  const __bf16* kbase = qbase + 1024;
  const __bf16* vtb = vt + (size_t)bh * 64 * SEQ;

  int q_g = qc * 64 + w * 32 + l31;

  int r8 = lane >> 3;
  int cxe = 8 * ((lane & 7) ^ r8);

  auto STAGE = [&](int bufv, int t) {
#pragma unroll
    for (int i = 0; i < 4; ++i) {
      int R = w * 32 + i * 8;
      GLL(kbase + (size_t)(t * 64 + R + r8) * 3072 + cxe, &K_lds[bufv][R][0]);
    }
  };

  bf16x8 qf[4];
#pragma unroll
  for (int ds = 0; ds < 4; ++ds)
    qf[ds] = *reinterpret_cast<const bf16x8*>(qbase + (size_t)q_g * 3072 + ds * 16 + 8 * hi);

  f32x16 oacc[2] = {};
  float l_run = 0.f;
  const float MFIX = 8.0f;

  if (NT > 0) STAGE(0, kv0);
  __syncthreads();

  int buf = 0;
  for (int jb = 0; jb < NT; ++jb) {
    int kt_g = kv0 + jb;
    bool pre = (jb + 1 < NT);
    if (pre) STAGE(buf ^ 1, kt_g + 1);

    // ---- V^T prefetch (global->reg) ----
    uint4 vr[8];
#pragma unroll
    for (int dt = 0; dt < 2; ++dt)
#pragma unroll
      for (int ks = 0; ks < 4; ++ks)
        vr[dt * 4 + ks] = *reinterpret_cast<const uint4*>(
            vtb + (size_t)(dt * 32 + l31) * SEQ + kt_g * 64 + ks * 16 + 8 * hi);

    // ---- S^T = K · Q^T ----
    f32x16 sacc[2] = {};
    __builtin_amdgcn_s_setprio(1);
#pragma unroll
    for (int kt = 0; kt < 2; ++kt) {
#pragma unroll
      for (int ds = 0; ds < 4; ++ds) {
        bf16x8 kf = *reinterpret_cast<const bf16x8*>(
            &K_lds[buf][kt * 32 + l31][(ds * 16 + 8 * hi) ^ ((l31 & 7) * 8)]);
        sacc[kt] = __builtin_amdgcn_mfma_f32_32x32x16_bf16(kf, qf[ds], sacc[kt], 0, 0, 0);
      }
    }
    __builtin_amdgcn_s_setprio(0);

    // ---- causal mask on the diagonal tile ----
    if (kt_g == qc) {
#pragma unroll
      for (int kt = 0; kt < 2; ++kt)
#pragma unroll
        for (int r = 0; r < 16; ++r) {
          int k_g = kt_g * 64 + kt * 32 + (r & 3) + 8 * (r >> 2) + 4 * hi;
          if (k_g > q_g) sacc[kt][r] = -1e30f;
        }
    }

    // ---- p = exp2(s - MFIX); 4 parallel sum chains ----
    float s0 = 0.f, s1 = 0.f, s2 = 0.f, s3 = 0.f;
#pragma unroll
    for (int kt = 0; kt < 2; ++kt) {
#pragma unroll
      for (int r = 0; r < 16; r += 4) {
        float p0 = exp2f(sacc[kt][r + 0] - MFIX);
        float p1 = exp2f(sacc[kt][r + 1] - MFIX);
        float p2 = exp2f(sacc[kt][r + 2] - MFIX);
        float p3 = exp2f(sacc[kt][r + 3] - MFIX);
        sacc[kt][r + 0] = p0; sacc[kt][r + 1] = p1;
        sacc[kt][r + 2] = p2; sacc[kt][r + 3] = p3;
        s0 += p0; s1 += p1; s2 += p2; s3 += p3;
      }
    }
    float sum = (s0 + s1) + (s2 + s3);
    sum += __shfl_xor(sum, 32);
    l_run += sum;

    // ---- build P fragments ----
    uint4 pa[4];
#pragma unroll
    for (int ks = 0; ks < 4; ++ks) {
      int v0 = 2 * ks, v1 = v0 + 1;
      int t0 = v0 >> 2, rb0 = 4 * (v0 & 3);
      int t1 = v1 >> 2, rb1 = 4 * (v1 & 3);
      uint32_t a01, a23, b01, b23;
      if (t0 == 0) { a01 = pkbf(sacc[0][rb0 + 0], sacc[0][rb0 + 1]);
                     a23 = pkbf(sacc[0][rb0 + 2], sacc[0][rb0 + 3]); }
      else         { a01 = pkbf(sacc[1][rb0 + 0], sacc[1][rb0 + 1]);
                     a23 = pkbf(sacc[1][rb0 + 2], sacc[1][rb0 + 3]); }
      if (t1 == 0) { b01 = pkbf(sacc[0][rb1 + 0], sacc[0][rb1 + 1]);
                     b23 = pkbf(sacc[0][rb1 + 2], sacc[0][rb1 + 3]); }
      else         { b01 = pkbf(sacc[1][rb1 + 0], sacc[1][rb1 + 1]);
                     b23 = pkbf(sacc[1][rb1 + 2], sacc[1][rb1 + 3]); }
      uint32_t t01 = hi ? a01 : b01;
      uint32_t t23 = hi ? a23 : b23;
      uint32_t r01 = __shfl_xor(t01, 32);
      uint32_t r23 = __shfl_xor(t23, 32);
      uint32_t k01 = hi ? b01 : a01;
      uint32_t k23 = hi ? b23 : a23;
      pa[ks].x = hi ? r01 : k01;
      pa[ks].y = hi ? r23 : k23;
      pa[ks].z = hi ? k01 : r01;
      pa[ks].w = hi ? k23 : r23;
    }

    // ---- O^T += V^T · P^T (V from regs) ----
    __builtin_amdgcn_s_setprio(1);
#pragma unroll
    for (int dt = 0; dt < 2; ++dt) {
#pragma unroll
      for (int ks = 0; ks < 4; ++ks) {
        oacc[dt] = __builtin_amdgcn_mfma_f32_32x32x16_bf16(
            *reinterpret_cast<const bf16x8*>(&vr[dt * 4 + ks]),
            *reinterpret_cast<const bf16x8*>(&pa[ks]), oacc[dt], 0, 0, 0);
      }
    }
    __builtin_amdgcn_s_setprio(0);

    if (pre) {
      asm volatile("s_waitcnt vmcnt(0)" ::: "memory");
      __syncthreads();
    }
    buf ^= 1;
  }

  // partial: unnormalized O^T (bf16) + l  (ALL items)
  int gi = ((31 - qc) * 2 + half) * 32 + bh;
  int q_local = w * 32 + l31;
  __bf16* pobase = slot_base(gi, qkv, xbf, q_local);
#pragma unroll
  for (int dt = 0; dt < 2; ++dt)
#pragma unroll
    for (int u = 0; u < 4; ++u) {
      int d0 = dt * 32 + 8 * u + 4 * hi;
      alignas(8) __bf16 tmp[4];
#pragma unroll
      for (int m = 0; m < 4; ++m) tmp[m] = (__bf16)oacc[dt][4 * u + m];
      *reinterpret_cast<uint2*>(pobase + d0) = *reinterpret_cast<const uint2*>(tmp);
    }
  if (hi == 0) pml[gi * 128 + q_local] = l_run;
}

// ---------------- combine halves (static max => pure l-weighting) ----------------
__global__ __launch_bounds__(128) void combine_kernel(__bf16* __restrict__ qkv,
                                                      __bf16* __restrict__ xbf,
                                                      const float* __restrict__ pml) {
  int bid = blockIdx.x;  // 1024 = 32 qc * 32 bh
  int qc = 31 - (bid >> 5), bh = bid & 31;
  int b = bh >> 4, h = bh & 15;
  int t = threadIdx.x;
  int q = t >> 1, dh = (t & 1) * 32;

  int g0 = ((31 - qc) * 2 + 0) * 32 + bh;
  int g1 = g0 + 32;
  float l0 = pml[g0 * 128 + q];
  float l1 = pml[g1 * 128 + q];
  float inv = 1.0f / (l0 + l1);

  const __bf16* p0 = slot_base(g0, qkv, xbf, q) + dh;
  const __bf16* p1 = slot_base(g1, qkv, xbf, q) + dh;
  __bf16* yq = qkv + (size_t)(b * SEQ + qc * 64 + q) * 3072 + h * 64 + dh;

#pragma unroll
  for (int c = 0; c < 4; ++c) {
    uint4 ua = *reinterpret_cast<const uint4*>(p0 + c * 8);
    uint4 ub = *reinterpret_cast<const uint4*>(p1 + c * 8);
    const __bf16* va = reinterpret_cast<const __bf16*>(&ua);
    const __bf16* vb = reinterpret_cast<const __bf16*>(&ub);
    alignas(16) __bf16 outv[8];
#pragma unroll
    for (int j = 0; j < 8; ++j)
      outv[j] = (__bf16)((((float)va[j]) + ((float)vb[j])) * inv);
    *reinterpret_cast<uint4*>(yq + c * 8) = *reinterpret_cast<const uint4*>(outv);
  }
}

extern "C" void kernel_launch(void* const* d_in, const int* in_sizes, int n_in,
                              void* d_out, int out_size, void* d_ws, size_t ws_size,
                              hipStream_t stream) {
  const float* x = (const float*)d_in[0];
  const float* Wqkv = (const float*)d_in[1];
  const float* Wo = (const float*)d_in[2];
  float* out = (float*)d_out;

  // ws layout (bf16 element offsets)
  __bf16* ws = (__bf16*)d_ws;
  __bf16* WqkvT = ws;                           // [3072][1024]  6 MB
  __bf16* WoT = WqkvT + (size_t)3072 * 1024;    // [1024][1024]  2 MB
  __bf16* qkv = WoT + (size_t)1024 * 1024;      // [4096][3072] 24 MB (v-slot = partial slots)
  __bf16* xbf = qkv + (size_t)4096 * 3072;      // [4096][1024]  8 MB (partial slots 1024..2047)
  __bf16* vtb = xbf + (size_t)4096 * 1024;      // [32][64][2048] 8 MB
  float* pml = (float*)(vtb + (size_t)32 * 64 * SEQ);  // 2048*128 f32 = 1 MB
  float2* sct = (float2*)(pml + 2048 * 128);           // 2048*32 float2 = 512 KB

  // 1) prep
  prep_kernel<<<3328, 256, 0, stream>>>(x, Wqkv, Wo, xbf, WqkvT, WoT, sct);

  // 2) merged qkv gemm (512-thread, T2-swizzled LDS): qk RoPE'd -> qkv; v -> vtb
  gemm_bt_lds<__bf16, 128, 3><<<dim3(32, 24), 512, 0, stream>>>(
      xbf, WqkvT, qkv, 4096, 3072, 1024, 1024, 3072, sct, vtb);

  // 3) attention: 2048 blocks, every qc split in two halves
  attn_kernel<<<2048, 128, 0, stream>>>(qkv, vtb, xbf, pml);

  // 4) combine halves
  combine_kernel<<<1024, 128, 0, stream>>>(qkv, xbf, pml);

  // 5) out = y @ Wo (512-thread, T2-swizzled LDS)
  gemm_bt_lds<float, 64, 0><<<dim3(32, 16), 512, 0, stream>>>(
      qkv, WoT, out, 4096, 1024, 1024, 3072, 1024, sct, nullptr);
}